// Round 1
// baseline (761.547 us; speedup 1.0000x reference)
//
#include <hip/hip_runtime.h>
#include <hip/hip_bf16.h>

// MoE top-2 of 8 experts. T=8192 tokens, D=1024, H=4096.
// Pipeline: route(+cast x) -> scan -> scatter -> transpose w1,w2 -> GEMM1(relu) -> GEMM2(scatter-add).

#define T_TOK   8192
#define DIM     1024
#define NEXP    8
#define HID     4096
#define NASSIGN (T_TOK * 2)

typedef unsigned short ushort_t;
typedef __attribute__((ext_vector_type(8))) short bfrag;
typedef __attribute__((ext_vector_type(4))) float f32x4;

__device__ __forceinline__ ushort_t f2bf(float f) {
    union { float f; unsigned int u; } v; v.f = f;
    unsigned int r = v.u + 0x7FFFu + ((v.u >> 16) & 1u);
    return (ushort_t)(r >> 16);
}

__device__ __forceinline__ void async_load16(const void* g, void* l) {
    __builtin_amdgcn_global_load_lds(
        (const __attribute__((address_space(1))) unsigned int*)g,
        (__attribute__((address_space(3))) unsigned int*)l, 16, 0, 0);
}

// ---------------- routing: logits, top2, softmax, counts; also cast x->bf16 ----------------
__global__ __launch_bounds__(256)
void route_kern(const float* __restrict__ x, const float* __restrict__ wg,
                ushort_t* __restrict__ x_bf, int* __restrict__ topk,
                float* __restrict__ gates, int* __restrict__ counts)
{
    const int w = threadIdx.x >> 6, lane = threadIdx.x & 63;
    const int t = blockIdx.x * 4 + w;
    const float* xr = x + (size_t)t * DIM;
    float acc[8];
#pragma unroll
    for (int e = 0; e < 8; ++e) acc[e] = 0.f;

#pragma unroll
    for (int it = 0; it < 4; ++it) {
        const int j = it * 256 + lane * 4;
        float4 xv = *(const float4*)(xr + j);
        ushort4 xb;
        xb.x = f2bf(xv.x); xb.y = f2bf(xv.y); xb.z = f2bf(xv.z); xb.w = f2bf(xv.w);
        *(ushort4*)(x_bf + (size_t)t * DIM + j) = xb;
        const float xs[4] = {xv.x, xv.y, xv.z, xv.w};
#pragma unroll
        for (int jj = 0; jj < 4; ++jj) {
            float4 g0 = *(const float4*)(wg + (size_t)(j + jj) * 8);
            float4 g1 = *(const float4*)(wg + (size_t)(j + jj) * 8 + 4);
            acc[0] += xs[jj] * g0.x; acc[1] += xs[jj] * g0.y;
            acc[2] += xs[jj] * g0.z; acc[3] += xs[jj] * g0.w;
            acc[4] += xs[jj] * g1.x; acc[5] += xs[jj] * g1.y;
            acc[6] += xs[jj] * g1.z; acc[7] += xs[jj] * g1.w;
        }
    }
#pragma unroll
    for (int d = 1; d < 64; d <<= 1)
#pragma unroll
        for (int e = 0; e < 8; ++e) acc[e] += __shfl_xor(acc[e], d);

    if (lane == 0) {
        int i0 = 0; float v0 = acc[0];
#pragma unroll
        for (int e = 1; e < 8; ++e) if (acc[e] > v0) { v0 = acc[e]; i0 = e; }
        int i1 = -1; float v1 = -1e30f;
#pragma unroll
        for (int e = 0; e < 8; ++e) if (e != i0 && acc[e] > v1) { v1 = acc[e]; i1 = e; }
        float ex = __expf(v1 - v0);
        float inv = 1.f / (1.f + ex);
        topk[t * 2] = i0; topk[t * 2 + 1] = i1;
        gates[t * 2] = inv; gates[t * 2 + 1] = ex * inv;
        atomicAdd(&counts[i0], 1);
        atomicAdd(&counts[i1], 1);
    }
}

__global__ void scan_kern(const int* __restrict__ counts, int* __restrict__ offs,
                          int* __restrict__ cursors)
{
    if (threadIdx.x == 0) {
        int o = 0;
        for (int e = 0; e < NEXP; ++e) { offs[e] = o; cursors[e] = o; o += counts[e]; }
        offs[NEXP] = o;
    }
}

__global__ __launch_bounds__(256)
void scatter_kern(const int* __restrict__ topk, const float* __restrict__ gates,
                  int* __restrict__ cursors, int* __restrict__ tok_c,
                  float* __restrict__ gate_c)
{
    const int t = blockIdx.x * 256 + threadIdx.x;
#pragma unroll
    for (int k = 0; k < 2; ++k) {
        int e = topk[t * 2 + k];
        int pos = atomicAdd(&cursors[e], 1);
        tok_c[pos] = t;
        gate_c[pos] = gates[t * 2 + k];
    }
}

// ---------------- transpose + cast: in [E][K][N] f32 -> out [E][N][K] bf16 ----------------
__global__ __launch_bounds__(256)
void transp_kern(const float* __restrict__ in, ushort_t* __restrict__ out, int K, int N)
{
    __shared__ float tile[64][65];
    const int e = blockIdx.z;
    const size_t ibase = (size_t)e * K * N, obase = (size_t)e * N * K;
    const int k0 = blockIdx.y * 64, n0 = blockIdx.x * 64;
    const int tid = threadIdx.x;

    const int r = tid >> 4, c4 = (tid & 15) * 4;  // 16 rows/pass, float4 along n
#pragma unroll
    for (int p = 0; p < 4; ++p) {
        int kk = p * 16 + r;
        float4 v = *(const float4*)(in + ibase + (size_t)(k0 + kk) * N + n0 + c4);
        tile[kk][c4] = v.x; tile[kk][c4 + 1] = v.y; tile[kk][c4 + 2] = v.z; tile[kk][c4 + 3] = v.w;
    }
    __syncthreads();
    const int nr = tid >> 6, kc = tid & 63;       // 4 n-rows/pass, 64 k along row
#pragma unroll
    for (int p = 0; p < 16; ++p) {
        int nn = p * 4 + nr;
        out[obase + (size_t)(n0 + nn) * K + k0 + kc] = f2bf(tile[kc][nn]);
    }
}

// ---------------- grouped GEMM, 128x128x64 tiles, mfma 16x16x32 bf16 ----------------
// STAGE 1: A = x_bf gathered by token, C = relu -> h (bf16, compact rows)
// STAGE 2: A = h compact rows,        C = gate * y -> atomicAdd into out (f32)
template <int STAGE>
__global__ __launch_bounds__(256)
void gemm_kern(const ushort_t* __restrict__ A, const ushort_t* __restrict__ Bt,
               ushort_t* __restrict__ Hout, float* __restrict__ Out,
               const int* __restrict__ eoff, const int* __restrict__ tok_c,
               const float* __restrict__ gate_c, int K, int N)
{
    __shared__ ushort_t ldsA[128 * 64];
    __shared__ ushort_t ldsB[128 * 64];

    const int e = blockIdx.z;
    const int base = eoff[e];
    const int cnt = eoff[e + 1] - base;
    const int m0 = blockIdx.y * 128;
    if (m0 >= cnt) return;
    const int n0 = blockIdx.x * 128;

    const int tid = threadIdx.x;
    const int w = tid >> 6, lane = tid & 63;
    const int lhi = lane >> 4, llo = lane & 15;

    // staging chunk assignment: chunk ci = (i*4+w)*64+lane ; LDS linear [row][64 bf16]
    // G4/rule-21 swizzle: LDS stays linear, SOURCE byte-in-row is XORed with (row&7)<<4
    const ushort_t* asrc[4];
    const ushort_t* bsrc[4];
    int ldsoff[4];
    const ushort_t* Bbase = Bt + (size_t)e * (size_t)N * (size_t)K;
#pragma unroll
    for (int i = 0; i < 4; ++i) {
        int ci = ((i * 4 + w) << 6) + lane;
        int r = ci >> 3;
        int cb = (ci & 7) << 4;
        int sb = cb ^ ((r & 7) << 4);
        int gr = m0 + r; if (gr >= cnt) gr = cnt - 1;
        size_t arow = (STAGE == 1) ? (size_t)tok_c[base + gr] * DIM
                                   : (size_t)(base + gr) * HID;
        asrc[i] = A + arow + (sb >> 1);
        bsrc[i] = Bbase + (size_t)(n0 + r) * K + (sb >> 1);
        ldsoff[i] = (i * 4 + w) << 10;
    }

    f32x4 acc[4][4];
#pragma unroll
    for (int m = 0; m < 4; ++m)
#pragma unroll
        for (int n = 0; n < 4; ++n) acc[m][n] = (f32x4)(0.f);

    const int wr = (w >> 1) << 6;
    const int wc = (w & 1) << 6;

    for (int k0 = 0; k0 < K; k0 += 64) {
#pragma unroll
        for (int i = 0; i < 4; ++i) {
            async_load16(asrc[i] + k0, (char*)ldsA + ldsoff[i]);
            async_load16(bsrc[i] + k0, (char*)ldsB + ldsoff[i]);
        }
        __syncthreads();
#pragma unroll
        for (int s = 0; s < 2; ++s) {
            bfrag a[4], b[4];
            const int kb = (s << 6) + (lhi << 4);
#pragma unroll
            for (int m = 0; m < 4; ++m) {
                int row = wr + (m << 4) + llo;
                a[m] = *(const bfrag*)((const char*)ldsA + row * 128 + (kb ^ ((row & 7) << 4)));
            }
#pragma unroll
            for (int n = 0; n < 4; ++n) {
                int row = wc + (n << 4) + llo;
                b[n] = *(const bfrag*)((const char*)ldsB + row * 128 + (kb ^ ((row & 7) << 4)));
            }
#pragma unroll
            for (int m = 0; m < 4; ++m)
#pragma unroll
                for (int n = 0; n < 4; ++n)
                    acc[m][n] = __builtin_amdgcn_mfma_f32_16x16x32_bf16(a[m], b[n], acc[m][n], 0, 0, 0);
        }
        __syncthreads();
    }

    if (STAGE == 1) {
#pragma unroll
        for (int m = 0; m < 4; ++m)
#pragma unroll
            for (int i = 0; i < 4; ++i) {
                int row = wr + (m << 4) + (lhi << 2) + i;
                int gr = m0 + row;
                if (gr >= cnt) continue;
                size_t rb = (size_t)(base + gr) * HID + n0 + wc;
#pragma unroll
                for (int n = 0; n < 4; ++n) {
                    float v = acc[m][n][i];
                    Hout[rb + (n << 4) + llo] = f2bf(v > 0.f ? v : 0.f);
                }
            }
    } else {
#pragma unroll
        for (int m = 0; m < 4; ++m)
#pragma unroll
            for (int i = 0; i < 4; ++i) {
                int row = wr + (m << 4) + (lhi << 2) + i;
                int gr = m0 + row;
                if (gr >= cnt) continue;
                int tok = tok_c[base + gr];
                float g = gate_c[base + gr];
                size_t rb = (size_t)tok * DIM + n0 + wc;
#pragma unroll
                for (int n = 0; n < 4; ++n)
                    atomicAdd(&Out[rb + (n << 4) + llo], g * acc[m][n][i]);
            }
    }
}

extern "C" void kernel_launch(void* const* d_in, const int* in_sizes, int n_in,
                              void* d_out, int out_size, void* d_ws, size_t ws_size,
                              hipStream_t stream)
{
    const float* x  = (const float*)d_in[0];   // [4,2048,1024]
    const float* wg = (const float*)d_in[1];   // [1024,8]
    const float* w1 = (const float*)d_in[2];   // [8,1024,4096]
    const float* w2 = (const float*)d_in[3];   // [8,4096,1024]
    float* out = (float*)d_out;                // [4,2048,1024] f32

    char* ws = (char*)d_ws;
    // ws layout (bytes)
    ushort_t* x_bf = (ushort_t*)(ws + 0);              // 16,777,216
    ushort_t* w1t  = (ushort_t*)(ws + 16777216);       // 67,108,864  [E][4096][1024]
    ushort_t* w2t  = (ushort_t*)(ws + 83886080);       // 67,108,864  [E][1024][4096]
    ushort_t* h    = (ushort_t*)(ws + 150994944);      // 134,217,728 [16384][4096]
    char* ctrl     = ws + 285212672;
    int*   topk    = (int*)(ctrl);
    float* gates   = (float*)(ctrl + 65536);
    int*   tok_c   = (int*)(ctrl + 131072);
    float* gate_c  = (float*)(ctrl + 196608);
    int*   counts  = (int*)(ctrl + 262144);
    int*   offs    = (int*)(ctrl + 262144 + 64);
    int*   cursors = (int*)(ctrl + 262144 + 128);

    hipMemsetAsync(counts, 0, NEXP * sizeof(int), stream);
    hipMemsetAsync(out, 0, (size_t)T_TOK * DIM * sizeof(float), stream);

    route_kern<<<T_TOK / 4, 256, 0, stream>>>(x, wg, x_bf, topk, gates, counts);
    transp_kern<<<dim3(HID / 64, DIM / 64, NEXP), 256, 0, stream>>>(w1, w1t, DIM, HID);
    transp_kern<<<dim3(DIM / 64, HID / 64, NEXP), 256, 0, stream>>>(w2, w2t, HID, DIM);
    scan_kern<<<1, 64, 0, stream>>>(counts, offs, cursors);
    scatter_kern<<<T_TOK / 256, 256, 0, stream>>>(topk, gates, cursors, tok_c, gate_c);

    // GEMM1: h = relu(x_bf[tok] @ w1t^T)  -> [16384][4096] bf16
    gemm_kern<1><<<dim3(HID / 128, 64, NEXP), 256, 0, stream>>>(
        x_bf, w1t, h, nullptr, offs, tok_c, gate_c, DIM, HID);
    // GEMM2: out[tok] += gate * (h @ w2t^T)
    gemm_kern<2><<<dim3(DIM / 128, 64, NEXP), 256, 0, stream>>>(
        h, w2t, nullptr, out, offs, tok_c, gate_c, HID, DIM);
}